// Round 5
// baseline (165.362 us; speedup 1.0000x reference)
//
#include <hip/hip_runtime.h>
#include <math.h>

// Problem constants
#define BB 2
#define LL 512
#define HH 768
#define EE 512
#define RR 32768
#define H2 384
#define MM 1024   // B*E entity rows

typedef __attribute__((ext_vector_type(8))) short     bf16x8;  // MFMA A/B frag (4 VGPRs)
typedef __attribute__((ext_vector_type(4))) float     f32x4;   // MFMA C/D frag
typedef __attribute__((ext_vector_type(8))) unsigned short u16x8;

__device__ __forceinline__ unsigned short f2bf(float f) {
    unsigned int u = __float_as_uint(f);
    u = (u + 0x7FFFu + ((u >> 16) & 1u)) >> 16;   // round-to-nearest-even
    return (unsigned short)u;
}

// ---------------------------------------------------------------------------
// prep: blocks [0,3168) transpose+convert the 6 weight matrices [K][N] fp32
// -> [N][K] bf16; blocks [3168,4192) build X bf16 (concat(hidden@start, emb)).
// Block 0 additionally zero-inits hlin/tlin accumulators + loss/counter.
// ---------------------------------------------------------------------------
__global__ __launch_bounds__(256) void prep(
    const float* __restrict__ hW1, const float* __restrict__ tW1,
    const float* __restrict__ hW2, const float* __restrict__ tW2,
    const float* __restrict__ bilW,
    unsigned short* __restrict__ W1ht, unsigned short* __restrict__ W1tt,
    unsigned short* __restrict__ W2ht, unsigned short* __restrict__ W2tt,
    unsigned short* __restrict__ bW0t, unsigned short* __restrict__ bW1t,
    const float* __restrict__ hidden, const int* __restrict__ ent_start,
    const int* __restrict__ ent_label, const float* __restrict__ emb,
    unsigned short* __restrict__ Xbf, float* __restrict__ small)
{
    __shared__ unsigned short T[32 * 40];
    const int bid = blockIdx.x;
    const int t = threadIdx.x;

    if (bid == 0) {
        // zero hlin[2048] | tlin[2048] | loss_acc | counter
        #pragma unroll
        for (int i = t; i < 4096; i += 256) small[i] = 0.f;
        if (t == 0) { small[4096] = 0.f; ((int*)small)[4097] = 0; }
    }

    if (bid >= 3168) {
        // ---- build X[m] = concat(hidden[b, ent_start], emb[label]) as bf16
        const int m = bid - 3168;          // 0..1023
        if (t >= 192) return;
        const int b = m >> 9;
        const int idx = ent_start[m];
        const int lab = ent_label[m];
        float4 v0, v1;
        if (t < 96) {
            const float4* s = (const float4*)(hidden + (size_t)(b * LL + idx) * HH);
            v0 = s[2 * t]; v1 = s[2 * t + 1];
        } else {
            const float4* s = (const float4*)(emb + (size_t)lab * HH);
            v0 = s[2 * t - 192]; v1 = s[2 * t - 191];
        }
        u16x8 o;
        o[0] = f2bf(v0.x); o[1] = f2bf(v0.y); o[2] = f2bf(v0.z); o[3] = f2bf(v0.w);
        o[4] = f2bf(v1.x); o[5] = f2bf(v1.y); o[6] = f2bf(v1.z); o[7] = f2bf(v1.w);
        *(u16x8*)(Xbf + (size_t)m * 1536 + 8 * t) = o;
        return;
    }

    // ---- weight transpose
    const float* src; unsigned short* dst; int K, N, tile;
    if (bid < 1152)      { src = hW1;            dst = W1ht; K = 1536; N = 768; tile = bid; }
    else if (bid < 2304) { src = tW1;            dst = W1tt; K = 1536; N = 768; tile = bid - 1152; }
    else if (bid < 2592) { src = hW2;            dst = W2ht; K = 768;  N = 384; tile = bid - 2304; }
    else if (bid < 2880) { src = tW2;            dst = W2tt; K = 768;  N = 384; tile = bid - 2592; }
    else if (bid < 3024) { src = bilW;           dst = bW0t; K = 384;  N = 384; tile = bid - 2880; }
    else                 { src = bilW + 384*384; dst = bW1t; K = 384;  N = 384; tile = bid - 3024; }
    const int tn = N >> 5;
    const int n0 = (tile % tn) * 32;
    const int k0 = (tile / tn) * 32;

    const int r  = t >> 3;           // 0..31 (k within tile)
    const int c4 = (t & 7) * 4;      // 0..28 (n within tile)
    const float4 g = *(const float4*)(src + (size_t)(k0 + r) * N + n0 + c4);
    T[(c4 + 0) * 40 + r] = f2bf(g.x);
    T[(c4 + 1) * 40 + r] = f2bf(g.y);
    T[(c4 + 2) * 40 + r] = f2bf(g.z);
    T[(c4 + 3) * 40 + r] = f2bf(g.w);
    __syncthreads();
    const int n  = t >> 3;           // 0..31
    const int k4 = (t & 7) * 4;      // 0..28
    *(ushort4*)(dst + (size_t)(n0 + n) * K + k0 + k4) = *(ushort4*)&T[n * 40 + k4];
}

// ---------------------------------------------------------------------------
// bf16 MFMA GEMM. 64x64 tile, 256 threads (4 waves, 2x2), 16x16x32 MFMA.
// A: [M][lda] bf16 row-major; half 1 (n0>=Nh) uses k-offset aoff1 + Bt1.
// B: transposed [*][ldb] bf16; row index += (m0>>9)*bt_mrow (batch-blocked).
// Epilogue options:
//   BIAS/RELU: per-half bias + relu
//   WF32/WBF16: write fp32 Cf and/or bf16 Cb
//   LINACC: atomic-accumulate hlinA/tlinA[2m+o] += sum_cols v * linW[2(hf*384+nc)+o]
//   LINADD: v += hlinR[2row+hf] + tlinR[2mt+hf] + lin_b[hf]   (mt from col)
// ---------------------------------------------------------------------------
template<bool RELU, bool BIAS, bool WF32, bool WBF16, bool LINACC, bool LINADD>
__global__ __launch_bounds__(256) void gemm_mfma(
    const unsigned short* __restrict__ A, int lda, int aoff1,
    const unsigned short* __restrict__ Bt0, const unsigned short* __restrict__ Bt1,
    int ldb, int bt_mrow, int Nh,
    const float* __restrict__ bias0, const float* __restrict__ bias1,
    int K, float* __restrict__ Cf, unsigned short* __restrict__ Cb, int ldc,
    const float* __restrict__ linW, float* __restrict__ hlinA, float* __restrict__ tlinA,
    const float* __restrict__ hlinR, const float* __restrict__ tlinR,
    const float* __restrict__ lin_b)
{
    __shared__ unsigned short As[64 * 40];
    __shared__ unsigned short Bs[64 * 40];

    const int tid = threadIdx.x;
    const int n0 = blockIdx.x * 64;
    const int m0 = blockIdx.y * 64;
    const int hf = (n0 >= Nh) ? 1 : 0;
    const unsigned short* Bt = hf ? Bt1 : Bt0;
    const int nc0 = n0 - (hf ? Nh : 0);
    const int aoff = hf ? aoff1 : 0;

    const int sr = tid >> 2;            // 0..63
    const int sk = (tid & 3) * 8;       // 0,8,16,24

    const unsigned short* Ap = A + (size_t)(m0 + sr) * lda + aoff + sk;
    const unsigned short* Bp = Bt + (size_t)((m0 >> 9) * bt_mrow + nc0 + sr) * ldb + sk;

    const int lane = tid & 63;
    const int wave = tid >> 6;
    const int wm = (wave & 1) * 32;
    const int wn = (wave >> 1) * 32;
    const int l15 = lane & 15;
    const int quad = lane >> 4;

    f32x4 acc00 = {}, acc01 = {}, acc10 = {}, acc11 = {};

    for (int k0 = 0; k0 < K; k0 += 32) {
        const u16x8 av = *(const u16x8*)(Ap + k0);
        const u16x8 bv = *(const u16x8*)(Bp + k0);
        __syncthreads();
        *(u16x8*)&As[sr * 40 + sk] = av;
        *(u16x8*)&Bs[sr * 40 + sk] = bv;
        __syncthreads();
        const bf16x8 a0 = *(const bf16x8*)&As[(wm + l15) * 40 + quad * 8];
        const bf16x8 a1 = *(const bf16x8*)&As[(wm + 16 + l15) * 40 + quad * 8];
        const bf16x8 b0 = *(const bf16x8*)&Bs[(wn + l15) * 40 + quad * 8];
        const bf16x8 b1 = *(const bf16x8*)&Bs[(wn + 16 + l15) * 40 + quad * 8];
        acc00 = __builtin_amdgcn_mfma_f32_16x16x32_bf16(a0, b0, acc00, 0, 0, 0);
        acc01 = __builtin_amdgcn_mfma_f32_16x16x32_bf16(a0, b1, acc01, 0, 0, 0);
        acc10 = __builtin_amdgcn_mfma_f32_16x16x32_bf16(a1, b0, acc10, 0, 0, 0);
        acc11 = __builtin_amdgcn_mfma_f32_16x16x32_bf16(a1, b1, acc11, 0, 0, 0);
    }

    // ---- epilogue (C/D layout: col=lane&15, row=quad*4+reg)
    float bias_v[2] = {0.f, 0.f};
    if (BIAS) {
        const float* bb = hf ? bias1 : bias0;
        bias_v[0] = bb[nc0 + wn + l15];
        bias_v[1] = bb[nc0 + wn + 16 + l15];
    }
    float wl0[2], wl1[2];
    if (LINACC) {
        #pragma unroll
        for (int ni = 0; ni < 2; ++ni) {
            const int nc = nc0 + wn + ni * 16 + l15;
            const float* wp = linW + 2 * (hf * 384 + nc);
            wl0[ni] = wp[0]; wl1[ni] = wp[1];
        }
    }
    float la0[2][4] = {}, la1[2][4] = {};   // [mi][r] lin partials

    const f32x4 accs[2][2] = {{acc00, acc01}, {acc10, acc11}};
    #pragma unroll
    for (int mi = 0; mi < 2; ++mi) {
        #pragma unroll
        for (int ni = 0; ni < 2; ++ni) {
            const int col = n0 + wn + ni * 16 + l15;
            #pragma unroll
            for (int r = 0; r < 4; ++r) {
                const int row = m0 + wm + mi * 16 + quad * 4 + r;
                float v = accs[mi][ni][r];
                if (BIAS) v += bias_v[ni];
                if (RELU) v = fmaxf(v, 0.f);
                if (LINACC) { la0[mi][r] += v * wl0[ni]; la1[mi][r] += v * wl1[ni]; }
                if (LINADD) {
                    const int mt = (m0 >> 9) * bt_mrow + (nc0 + wn + ni * 16 + l15);
                    v += hlinR[2 * row + hf] + tlinR[2 * mt + hf] + lin_b[hf];
                }
                if (WF32) Cf[(size_t)row * ldc + col] = v;
                if (WBF16) Cb[(size_t)row * ldc + col] = f2bf(v);
            }
        }
    }

    if (LINACC) {
        // reduce over the 16 cols (l15) within each quad-group, then atomics
        #pragma unroll
        for (int mi = 0; mi < 2; ++mi)
            #pragma unroll
            for (int r = 0; r < 4; ++r) {
                float s0 = la0[mi][r], s1 = la1[mi][r];
                #pragma unroll
                for (int o = 8; o >= 1; o >>= 1) {
                    s0 += __shfl_xor(s0, o, 64);
                    s1 += __shfl_xor(s1, o, 64);
                }
                if (l15 == 0) {
                    const int row = m0 + wm + mi * 16 + quad * 4 + r;
                    float* dst = (hf ? tlinA : hlinA) + 2 * row;
                    atomicAdd(dst, s0);
                    atomicAdd(dst + 1, s1);
                }
            }
    }
}

// ---------------------------------------------------------------------------
// Per-relation gather from the logits table (lin terms already folded in)
// + CE, + last-block loss finalize.
// ---------------------------------------------------------------------------
__global__ __launch_bounds__(256) void rel_gather(
    const float* __restrict__ Stab,
    const int* __restrict__ rel_head, const int* __restrict__ rel_tail,
    const int* __restrict__ rel_label,
    float* __restrict__ out, float* __restrict__ loss_acc, int* __restrict__ counter)
{
    const int tid = threadIdx.x;
    const int i = blockIdx.x * 256 + tid;       // relation 0..65535
    const int b = i >> 15;
    const int h = rel_head[i];
    const int t = rel_tail[i];
    const int lab = rel_label[i];
    const int mh = (b << 9) + h;

    const float* srow = Stab + (size_t)mh * 1024;
    const float z0 = srow[t];
    const float z1 = srow[512 + t];
    out[1 + 2 * (size_t)i] = z0;
    out[2 + 2 * (size_t)i] = z1;

    const float mx = fmaxf(z0, z1);
    const float mn = fminf(z0, z1);
    const float lse = mx + log1pf(expf(mn - mx));
    float ce = lse - (lab ? z1 : z0);

    #pragma unroll
    for (int o = 32; o >= 1; o >>= 1) ce += __shfl_xor(ce, o, 64);
    __shared__ float wsum[4];
    if ((tid & 63) == 0) wsum[tid >> 6] = ce;
    __syncthreads();
    if (tid == 0) {
        const float s = wsum[0] + wsum[1] + wsum[2] + wsum[3];
        atomicAdd(loss_acc, s);
        __threadfence();
        const int old = atomicAdd(counter, 1);
        if (old == (int)gridDim.x - 1) {
            const float tot = atomicAdd(loss_acc, 0.0f);   // coherent read
            out[0] = tot * (1.0f / (float)RR);
        }
    }
}

// ---------------------------------------------------------------------------
extern "C" void kernel_launch(void* const* d_in, const int* in_sizes, int n_in,
                              void* d_out, int out_size, void* d_ws, size_t ws_size,
                              hipStream_t stream) {
    const float* hidden    = (const float*)d_in[0];
    const int*   ent_start = (const int*)d_in[1];
    const int*   ent_label = (const int*)d_in[2];
    const int*   rel_head  = (const int*)d_in[3];
    const int*   rel_tail  = (const int*)d_in[4];
    const int*   rel_label = (const int*)d_in[5];
    const float* emb       = (const float*)d_in[6];
    const float* head_W1   = (const float*)d_in[7];
    const float* head_b1   = (const float*)d_in[8];
    const float* head_W2   = (const float*)d_in[9];
    const float* head_b2   = (const float*)d_in[10];
    const float* tail_W1   = (const float*)d_in[11];
    const float* tail_b1   = (const float*)d_in[12];
    const float* tail_W2   = (const float*)d_in[13];
    const float* tail_b2   = (const float*)d_in[14];
    const float* bil_W     = (const float*)d_in[15];
    const float* lin_W     = (const float*)d_in[16];
    const float* lin_b     = (const float*)d_in[17];
    float* out = (float*)d_out;

    // Workspace carve-up (256B-aligned chunks)
    char* w = (char*)d_ws;
    auto carve = [&](size_t bytes) {
        char* p = w; w += (bytes + 255) & ~(size_t)255; return p;
    };
    unsigned short* Xbf  = (unsigned short*)carve((size_t)MM * 1536 * 2);
    unsigned short* Y1bf = (unsigned short*)carve((size_t)MM * 1536 * 2);
    unsigned short* HTbf = (unsigned short*)carve((size_t)MM * 768 * 2);
    unsigned short* hWbf = (unsigned short*)carve((size_t)MM * 768 * 2);
    float*          Stab = (float*)carve((size_t)MM * 1024 * 4);
    unsigned short* W1ht = (unsigned short*)carve((size_t)768 * 1536 * 2);
    unsigned short* W1tt = (unsigned short*)carve((size_t)768 * 1536 * 2);
    unsigned short* W2ht = (unsigned short*)carve((size_t)384 * 768 * 2);
    unsigned short* W2tt = (unsigned short*)carve((size_t)384 * 768 * 2);
    unsigned short* bW0t = (unsigned short*)carve((size_t)384 * 384 * 2);
    unsigned short* bW1t = (unsigned short*)carve((size_t)384 * 384 * 2);
    float*          small = (float*)carve(4112 * 4);  // hlin|tlin|loss|cnt
    float*          hlin  = small;
    float*          tlin  = small + 2048;
    float*          loss_acc = small + 4096;
    int*            counter  = (int*)(small + 4097);

    // 1) weight transpose->bf16 + X gather->bf16 + zero-init accumulators
    prep<<<4192, 256, 0, stream>>>(
        head_W1, tail_W1, head_W2, tail_W2, bil_W,
        W1ht, W1tt, W2ht, W2tt, bW0t, bW1t,
        hidden, ent_start, ent_label, emb, Xbf, small);

    // 2) layer1: Y1 = relu(X @ [W1h|W1t] + b1), N=1536 (Nh=768), K=1536
    gemm_mfma<true, true, false, true, false, false><<<dim3(24, 16), 256, 0, stream>>>(
        Xbf, 1536, 0, W1ht, W1tt, 1536, 0, 768, head_b1, tail_b1, 1536,
        nullptr, Y1bf, 1536, nullptr, nullptr, nullptr, nullptr, nullptr, nullptr);

    // 3) layer2: HTbf = relu(Y1 @ [W2h|W2t] + b2), N=768 (Nh=384), K=768,
    //    tail half reads Y1 cols 768..; epilogue also accumulates hlin/tlin
    gemm_mfma<true, true, false, true, true, false><<<dim3(12, 16), 256, 0, stream>>>(
        Y1bf, 1536, 768, W2ht, W2tt, 768, 0, 384, head_b2, tail_b2, 768,
        nullptr, HTbf, 768, lin_W, hlin, tlin, nullptr, nullptr, nullptr);

    // 4) bilinear left product: hWbf = heads @ bil_W[o], N=768 (Nh=384), K=384
    gemm_mfma<false, false, false, true, false, false><<<dim3(12, 16), 256, 0, stream>>>(
        HTbf, 768, 0, bW0t, bW1t, 384, 0, 384, nullptr, nullptr, 384,
        nullptr, hWbf, 768, nullptr, nullptr, nullptr, nullptr, nullptr, nullptr);

    // 5) logits table: Stab[mh][o*512+t] = hWbf[mh,o..] . tails[b,t,:]
    //                   + hlin[mh,o] + tlin[mt,o] + lin_b[o]
    gemm_mfma<false, false, true, false, false, true><<<dim3(16, 16), 256, 0, stream>>>(
        hWbf, 768, 384, HTbf + 384, HTbf + 384, 768, 512, 512,
        nullptr, nullptr, 384, Stab, nullptr, 1024,
        nullptr, nullptr, nullptr, hlin, tlin, lin_b);

    // 6) per-relation gather + CE + fused loss finalize
    rel_gather<<<256, 256, 0, stream>>>(Stab, rel_head, rel_tail, rel_label,
                                        out, loss_acc, counter);
}